// Round 3
// baseline (6991.882 us; speedup 1.0000x reference)
//
#include <hip/hip_runtime.h>
#include <hip/hip_bf16.h>

#define TT 4096
#define FF 80
#define HH 64
#define NB 128           // batch
#define TB 256           // timesteps per projection block

__device__ __forceinline__ float sigm(float x) {
    return __builtin_amdgcn_rcpf(1.0f + __expf(-x));
}
__device__ __forceinline__ float tanh_f(float x) {
    return 1.0f - 2.0f * __builtin_amdgcn_rcpf(1.0f + __expf(2.0f * x));
}

__device__ __forceinline__ float ldv(const float* p) { return *p; }
__device__ __forceinline__ float ldv(const __hip_bfloat16* p) { return __bfloat162float(*p); }
__device__ __forceinline__ void stv(float* p, float v) { *p = v; }
__device__ __forceinline__ void stv(__hip_bfloat16* p, float v) { *p = __float2bfloat16(v); }

// LDS-visibility-only barrier: does NOT drain vmcnt, so global prefetch
// loads stay in flight across it (the __syncthreads() vmcnt(0) drain was
// costing a full memory latency per timestep).
__device__ __forceinline__ void bar_lgkm() {
    asm volatile("s_waitcnt lgkmcnt(0)" ::: "memory");
    __builtin_amdgcn_s_barrier();
    asm volatile("" ::: "memory");
}

// ---------------------------------------------------------------------------
// Projection: PRE[dir][b][t][k] = b_ih[k]+b_hh[k] + sum_f w_ih[k][f]*x[b][te][f]
// te = t (fwd) or TT-1-t (bwd). No LDS: x addresses are wave-uniform, so the
// compiler scalarizes them (s_load / L1 broadcast); weights live in VGPRs.
// ---------------------------------------------------------------------------
template <typename ST>
__global__ __launch_bounds__(256)
void lstm_proj_kernel(const float* __restrict__ x,
                      const float* __restrict__ w_ih_f, const float* __restrict__ b_ih_f,
                      const float* __restrict__ b_hh_f,
                      const float* __restrict__ w_ih_b, const float* __restrict__ b_ih_b,
                      const float* __restrict__ b_hh_b,
                      ST* __restrict__ pre)            // [2][NB][TT][256]
{
    const int blk  = blockIdx.x;          // 2 * NB * (TT/TB) = 4096
    const int tile = blk & (TT / TB - 1); // 16 tiles
    const int bat  = (blk >> 4) & (NB - 1);
    const int dir  = blk >> 11;
    const int tid  = threadIdx.x;         // gate index k
    const int t0   = tile * TB;

    const float* __restrict__ w_ih = dir ? w_ih_b : w_ih_f;
    const float  bias = (dir ? b_ih_b[tid] + b_hh_b[tid] : b_ih_f[tid] + b_hh_f[tid]);

    float4 wi4[FF / 4];
    const float4* wr = reinterpret_cast<const float4*>(w_ih + tid * FF);
    #pragma unroll
    for (int q = 0; q < FF / 4; ++q) wi4[q] = wr[q];

    const float4* __restrict__ xr4 =
        reinterpret_cast<const float4*>(x + (size_t)bat * (TT * FF));
    ST* __restrict__ prow = pre + ((size_t)(dir * NB + bat) * TT) * 256 + tid;

    #pragma unroll 2
    for (int tt = 0; tt < TB; ++tt) {
        const int t  = t0 + tt;
        const int te = dir ? (TT - 1 - t) : t;
        const float4* __restrict__ xv = xr4 + (size_t)te * (FF / 4);
        float a0 = bias, a1 = 0.f, a2 = 0.f, a3 = 0.f;
        #pragma unroll
        for (int q = 0; q < FF / 4; ++q) {
            const float4 v = xv[q];           // wave-uniform -> s_load/L1 broadcast
            a0 = fmaf(wi4[q].x, v.x, a0);
            a1 = fmaf(wi4[q].y, v.y, a1);
            a2 = fmaf(wi4[q].z, v.z, a2);
            a3 = fmaf(wi4[q].w, v.w, a3);
        }
        stv(prow + (size_t)t * 256, (a0 + a1) + (a2 + a3));
    }
}

// ---------------------------------------------------------------------------
// Recurrent scan. One block per (dir,batch), 256 threads, thread k = gate k,
// W_hh row register-resident. Raw lgkm-only barrier keeps the distance-4 PRE
// prefetch in flight across steps. gbufT[parity][unit][gate] gives the
// activation phase a single conflict-free ds_read_b128 per lane.
// ---------------------------------------------------------------------------
template <typename ST>
__global__ __launch_bounds__(256, 1)
void lstm_scan_pre_kernel(const ST* __restrict__ pre,
                          const float* __restrict__ w_hh_f, const float* __restrict__ w_hh_b,
                          float* __restrict__ h_out)   // [2][NB][HH]
{
    const int blk = blockIdx.x;        // 0..255
    const int dir = blk >> 7;
    const int bat = blk & (NB - 1);
    const int tid = threadIdx.x;       // gate index k
    const int wv  = tid >> 6;          // gate type (i,f,g,o)
    const int ln  = tid & 63;          // hidden unit

    const float* __restrict__ w_hh = dir ? w_hh_b : w_hh_f;
    float4 wh4[HH / 4];
    const float4* whr = reinterpret_cast<const float4*>(w_hh + tid * HH);
    #pragma unroll
    for (int j = 0; j < HH / 4; ++j) wh4[j] = whr[j];

    __shared__ float hbuf[4][HH];        // per-wave private h copy
    __shared__ float gbufT[2][HH][4];    // [parity][unit][gate], b128-readable

    float c = 0.0f, h = 0.0f;
    hbuf[wv][ln] = 0.0f;

    const ST* __restrict__ prow = pre + ((size_t)(dir * NB + bat) * TT) * 256 + tid;
    // distance-4 prefetch pipeline, statically rotated (loop unrolled by 4)
    float p0 = ldv(prow);
    float p1 = ldv(prow + 256);
    float p2 = ldv(prow + 2 * 256);
    float p3 = ldv(prow + 3 * 256);
    __syncthreads();   // one full barrier before the loop is fine

    #pragma unroll 4
    for (int t = 0; t < TT; ++t) {
        const int cur = t & 1;

        float a0 = p0, a1 = 0.f, a2 = 0.f, a3 = 0.f;
        p0 = p1; p1 = p2; p2 = p3;
        if (t + 4 < TT) p3 = ldv(prow + (size_t)(t + 4) * 256);

        const float4* hb4 = reinterpret_cast<const float4*>(hbuf[wv]);
        #pragma unroll
        for (int j = 0; j < HH / 4; ++j) {
            const float4 v = hb4[j];
            a0 = fmaf(wh4[j].x, v.x, a0);
            a1 = fmaf(wh4[j].y, v.y, a1);
            a2 = fmaf(wh4[j].z, v.z, a2);
            a3 = fmaf(wh4[j].w, v.w, a3);
        }
        gbufT[cur][ln][wv] = (a0 + a1) + (a2 + a3);

        bar_lgkm();                      // LDS-visibility only; vmcnt stays live

        const float4 g4 = *reinterpret_cast<const float4*>(gbufT[cur][ln]);
        c = sigm(g4.y) * c + sigm(g4.x) * tanh_f(g4.z);
        h = sigm(g4.w) * tanh_f(c);
        hbuf[wv][ln] = h;                // own-wave buffer; in-order DS = no wait
    }

    if (tid < HH) h_out[(size_t)(dir * NB + bat) * HH + tid] = h;
}

// ---------------------------------------------------------------------------
// Fallback: fully fused scan (round-1 kernel) if ws is too small for PRE.
// ---------------------------------------------------------------------------
__global__ __launch_bounds__(256, 1)
void lstm_scan_fused_kernel(const float* __restrict__ x,
                            const float* __restrict__ w_ih_f, const float* __restrict__ w_hh_f,
                            const float* __restrict__ b_ih_f, const float* __restrict__ b_hh_f,
                            const float* __restrict__ w_ih_b, const float* __restrict__ w_hh_b,
                            const float* __restrict__ b_ih_b, const float* __restrict__ b_hh_b,
                            float* __restrict__ h_out)
{
    const int blk = blockIdx.x;
    const int dir = blk >> 7;
    const int bat = blk & 127;
    const int tid = threadIdx.x;
    const int wv  = tid >> 6;
    const int ln  = tid & 63;

    const float* __restrict__ w_ih = dir ? w_ih_b : w_ih_f;
    const float* __restrict__ w_hh = dir ? w_hh_b : w_hh_f;
    const float* __restrict__ b_ih = dir ? b_ih_b : b_ih_f;
    const float* __restrict__ b_hh = dir ? b_hh_b : b_hh_f;

    float wi[FF], wh[HH];
    #pragma unroll
    for (int f = 0; f < FF; ++f) wi[f] = w_ih[tid * FF + f];
    #pragma unroll
    for (int j = 0; j < HH; ++j) wh[j] = w_hh[tid * HH + j];
    const float bias = b_ih[tid] + b_hh[tid];

    __shared__ float xs[2][FF];
    __shared__ float hbuf[4][HH];
    __shared__ float gbuf[2][256];

    const float* __restrict__ xrow = x + (size_t)bat * (TT * FF);
    float c = 0.0f, hreg = 0.0f;
    hbuf[wv][ln] = 0.0f;

    float xA = 0.0f;
    if (tid < FF) {
        xs[0][tid] = xrow[(size_t)(dir ? (TT - 1) : 0) * FF + tid];
        xA         = xrow[(size_t)(dir ? (TT - 2) : 1) * FF + tid];
    }
    __syncthreads();

    #pragma unroll 1
    for (int t = 0; t < TT; ++t) {
        const int cur = t & 1, nxt = cur ^ 1;
        float a0 = 0.f, a1 = 0.f, a2 = 0.f, a3 = 0.f;
        const float4* xs4 = reinterpret_cast<const float4*>(xs[cur]);
        #pragma unroll
        for (int f = 0; f < FF / 4; ++f) {
            float4 v = xs4[f];
            a0 = fmaf(wi[4*f+0], v.x, a0);
            a1 = fmaf(wi[4*f+1], v.y, a1);
            a2 = fmaf(wi[4*f+2], v.z, a2);
            a3 = fmaf(wi[4*f+3], v.w, a3);
        }
        const float4* hb4 = reinterpret_cast<const float4*>(hbuf[wv]);
        #pragma unroll
        for (int j = 0; j < HH / 4; ++j) {
            float4 v = hb4[j];
            a0 = fmaf(wh[4*j+0], v.x, a0);
            a1 = fmaf(wh[4*j+1], v.y, a1);
            a2 = fmaf(wh[4*j+2], v.z, a2);
            a3 = fmaf(wh[4*j+3], v.w, a3);
        }
        gbuf[cur][tid] = ((a0 + a1) + (a2 + a3)) + bias;

        if (tid < FF) {
            if (t + 1 < TT) xs[nxt][tid] = xA;
            if (t + 2 < TT) xA = xrow[(size_t)(dir ? (TT - 3 - t) : (t + 2)) * FF + tid];
        }
        __syncthreads();

        const float gi = gbuf[cur][ln];
        const float gf = gbuf[cur][64 + ln];
        const float gg = gbuf[cur][128 + ln];
        const float go = gbuf[cur][192 + ln];
        c    = sigm(gf) * c + sigm(gi) * tanh_f(gg);
        hreg = sigm(go) * tanh_f(c);
        hbuf[wv][ln] = hreg;
    }

    if (tid < HH) h_out[(size_t)(dir * 128 + bat) * HH + tid] = hreg;
}

__global__ __launch_bounds__(64, 1)
void fc_kernel(const float* __restrict__ h_out,   // [2][NB][HH]
               const float* __restrict__ w_fc,    // [8][128]
               const float* __restrict__ b_fc,    // [8]
               float* __restrict__ out)           // [NB][8]
{
    const int b = blockIdx.x;
    const int o = threadIdx.x;
    if (o < 8) {
        float acc = b_fc[o];
        #pragma unroll 4
        for (int j = 0; j < HH; ++j)
            acc = fmaf(h_out[(size_t)b * HH + j], w_fc[o * 128 + j], acc);
        #pragma unroll 4
        for (int j = 0; j < HH; ++j)
            acc = fmaf(h_out[(size_t)(NB + b) * HH + j], w_fc[o * 128 + 64 + j], acc);
        out[b * 8 + o] = acc;
    }
}

extern "C" void kernel_launch(void* const* d_in, const int* in_sizes, int n_in,
                              void* d_out, int out_size, void* d_ws, size_t ws_size,
                              hipStream_t stream) {
    const float* x      = (const float*)d_in[0];
    const float* w_ih_f = (const float*)d_in[2];
    const float* w_hh_f = (const float*)d_in[3];
    const float* b_ih_f = (const float*)d_in[4];
    const float* b_hh_f = (const float*)d_in[5];
    const float* w_ih_b = (const float*)d_in[6];
    const float* w_hh_b = (const float*)d_in[7];
    const float* b_ih_b = (const float*)d_in[8];
    const float* b_hh_b = (const float*)d_in[9];
    const float* w_fc   = (const float*)d_in[10];
    const float* b_fc   = (const float*)d_in[11];
    float* out = (float*)d_out;

    const size_t pre_elems = (size_t)2 * NB * TT * 256;
    const size_t need_f32  = pre_elems * sizeof(float) + 64 * 1024;
    const size_t need_bf16 = pre_elems * sizeof(__hip_bfloat16) + 64 * 1024;
    const int    nproj     = 2 * NB * (TT / TB);   // 4096 blocks

    if (ws_size >= need_f32) {
        float* pre   = (float*)d_ws;
        float* h_out = (float*)((char*)d_ws + pre_elems * sizeof(float));
        lstm_proj_kernel<float><<<dim3(nproj), dim3(256), 0, stream>>>(
            x, w_ih_f, b_ih_f, b_hh_f, w_ih_b, b_ih_b, b_hh_b, pre);
        lstm_scan_pre_kernel<float><<<dim3(256), dim3(256), 0, stream>>>(
            pre, w_hh_f, w_hh_b, h_out);
        fc_kernel<<<dim3(128), dim3(64), 0, stream>>>(h_out, w_fc, b_fc, out);
    } else if (ws_size >= need_bf16) {
        __hip_bfloat16* pre = (__hip_bfloat16*)d_ws;
        float* h_out = (float*)((char*)d_ws + pre_elems * sizeof(__hip_bfloat16));
        lstm_proj_kernel<__hip_bfloat16><<<dim3(nproj), dim3(256), 0, stream>>>(
            x, w_ih_f, b_ih_f, b_hh_f, w_ih_b, b_ih_b, b_hh_b, pre);
        lstm_scan_pre_kernel<__hip_bfloat16><<<dim3(256), dim3(256), 0, stream>>>(
            pre, w_hh_f, w_hh_b, h_out);
        fc_kernel<<<dim3(128), dim3(64), 0, stream>>>(h_out, w_fc, b_fc, out);
    } else {
        float* h_out = (float*)d_ws;   // 64 KiB
        lstm_scan_fused_kernel<<<dim3(256), dim3(256), 0, stream>>>(
            x, w_ih_f, w_hh_f, b_ih_f, b_hh_f,
            w_ih_b, w_hh_b, b_ih_b, b_hh_b, h_out);
        fc_kernel<<<dim3(128), dim3(64), 0, stream>>>(h_out, w_fc, b_fc, out);
    }
}

// Round 4
// 2716.470 us; speedup vs baseline: 2.5739x; 2.5739x over previous
//
#include <hip/hip_runtime.h>
#include <hip/hip_bf16.h>

#define TT 4096
#define FF 80
#define HH 64
#define NB 128
#define TB 256    // proj: timesteps per block
#define CT 8      // proj: timesteps per staging phase
#define XPAD 104  // proj LDS row stride in bf16 elems (bank-friendly, 16B-divisible*2)

using short8  = __attribute__((ext_vector_type(8))) short;   // 8 bf16 = 4 VGPR
using floatx4 = __attribute__((ext_vector_type(4))) float;

__device__ __forceinline__ float sigm(float x)  { return __builtin_amdgcn_rcpf(1.0f + __expf(-x)); }
__device__ __forceinline__ float tanh_f(float x){ return 1.0f - 2.0f * __builtin_amdgcn_rcpf(1.0f + __expf(2.0f * x)); }

__device__ __forceinline__ short f2bf(float f) {             // RNE f32->bf16
    unsigned u = __builtin_bit_cast(unsigned, f);
    u += 0x7fffu + ((u >> 16) & 1u);
    return (short)(u >> 16);
}
__device__ __forceinline__ float bflo(unsigned u) { return __builtin_bit_cast(float, u << 16); }
__device__ __forceinline__ float bfhi(unsigned u) { return __builtin_bit_cast(float, u & 0xffff0000u); }
__device__ __forceinline__ unsigned packbf2(float a, float b) {
    return (unsigned)(unsigned short)f2bf(a) | ((unsigned)(unsigned short)f2bf(b) << 16);
}

// LDS-visibility-only barrier: global loads/stores stay in flight across it.
__device__ __forceinline__ void bar_lgkm() {
    asm volatile("s_waitcnt lgkmcnt(0)" ::: "memory");
    __builtin_amdgcn_s_barrier();
}

__device__ __forceinline__ floatx4 mfma16(short8 a, short8 b, floatx4 c) {
    return __builtin_amdgcn_mfma_f32_16x16x32_bf16(a, b, c, 0, 0, 0);
}

// ---------------------------------------------------------------------------
// PROJ (MFMA): PRE[dgrp][t][n 0..255][b 0..15] (bf16) =
//   bias[n] + sum_f x[bgrp*16+b][te][f] * w_ih[n][f],  te = t (fwd) / TT-1-t (bwd)
// Block = (dgrp = dir*8+bgrp, ttile). A = x rows (16 batches), B = w_ih^T,
// K = 80 zero-padded to 96 (3 chunks of 32). B-frags register-resident.
// ---------------------------------------------------------------------------
__global__ __launch_bounds__(256, 1)
void lstm_proj_mfma(const float* __restrict__ x,
                    const float* __restrict__ w_ih_f, const float* __restrict__ b_ih_f,
                    const float* __restrict__ b_hh_f,
                    const float* __restrict__ w_ih_b, const float* __restrict__ b_ih_b,
                    const float* __restrict__ b_hh_b,
                    __hip_bfloat16* __restrict__ pre)
{
    const int blk   = blockIdx.x;        // 256 = 16 dgrp x 16 ttile
    const int ttile = blk & 15;
    const int dgrp  = blk >> 4;
    const int dir   = dgrp >> 3;
    const int bgrp  = dgrp & 7;
    const int tid   = threadIdx.x;
    const int wv    = tid >> 6;
    const int l     = tid & 63;
    const int b16   = l & 15;            // A row (batch) / C col (n within tile)
    const int g     = l >> 4;            // k-group / C row group
    const int t0    = ttile * TB;

    const float* __restrict__ wih = dir ? w_ih_b : w_ih_f;
    const float* __restrict__ bi  = dir ? b_ih_b : b_ih_f;
    const float* __restrict__ bh  = dir ? b_hh_b : b_hh_f;

    // B-fragments: wave wv owns tiles tau = 4*wv + tp. col n = 16*tau + b16,
    // k = 32*kap + 8*g + j (zero for k >= 80).
    short8 Bf[4][3];
    float  bias[4];
    #pragma unroll
    for (int tp = 0; tp < 4; ++tp) {
        const int n = 64 * wv + 16 * tp + b16;
        bias[tp] = bi[n] + bh[n];
        #pragma unroll
        for (int kap = 0; kap < 3; ++kap) {
            const int f0 = 32 * kap + 8 * g;
            float f[8];
            if (f0 < FF) {
                const float4 v0 = *reinterpret_cast<const float4*>(wih + n * FF + f0);
                const float4 v1 = *reinterpret_cast<const float4*>(wih + n * FF + f0 + 4);
                f[0]=v0.x; f[1]=v0.y; f[2]=v0.z; f[3]=v0.w;
                f[4]=v1.x; f[5]=v1.y; f[6]=v1.z; f[7]=v1.w;
            } else {
                #pragma unroll
                for (int j = 0; j < 8; ++j) f[j] = 0.0f;
            }
            short8 s;
            #pragma unroll
            for (int j = 0; j < 8; ++j) s[j] = f2bf(f[j]);
            Bf[tp][kap] = s;
        }
    }

    // x staging LDS: [buf][CT t][16 b][XPAD] bf16; cols 80..103 stay zero.
    __shared__ __align__(16) __hip_bfloat16 xa[2][CT][16][XPAD];
    for (int i = tid; i < 2 * CT * 16 * XPAD / 2; i += 256)
        reinterpret_cast<unsigned*>(&xa[0][0][0][0])[i] = 0u;
    __syncthreads();

    const int nph = TB / CT;   // 32

    // ---- staging helper (inline twice): 20 float2 loads -> pack -> ds_write
    // i = q*256+tid: b = i/320, r2 = i%320, te_rel = r2/40, fq = r2%40
    // te_base: fwd t0p ; bwd TT-CT-t0p.  t_off = dir ? CT-1-te_rel : te_rel
    {   // prologue: stage phase 0 into xa[0]
        const int t0p = t0;
        const int te_base = dir ? (TT - CT - t0p) : t0p;
        float2 st[20];
        #pragma unroll
        for (int q = 0; q < 20; ++q) {
            const int i = q * 256 + tid;
            const int b = i / 320, r2 = i % 320;
            const int te_rel = r2 / 40, fq = r2 % 40;
            st[q] = *reinterpret_cast<const float2*>(
                x + ((size_t)(bgrp * 16 + b) * TT + te_base + te_rel) * FF + 2 * fq);
        }
        #pragma unroll
        for (int q = 0; q < 20; ++q) {
            const int i = q * 256 + tid;
            const int b = i / 320, r2 = i % 320;
            const int te_rel = r2 / 40, fq = r2 % 40;
            const int t_off = dir ? (CT - 1 - te_rel) : te_rel;
            *reinterpret_cast<unsigned*>(&xa[0][t_off][b][2 * fq]) = packbf2(st[q].x, st[q].y);
        }
    }
    __syncthreads();

    #pragma unroll 1
    for (int ph = 0; ph < nph; ++ph) {
        const int cur = ph & 1;
        const bool have = (ph + 1) < nph;

        // 1) issue next-phase global loads early (hide under MFMA phase)
        float2 st[20];
        if (have) {
            const int t0p = t0 + (ph + 1) * CT;
            const int te_base = dir ? (TT - CT - t0p) : t0p;
            #pragma unroll
            for (int q = 0; q < 20; ++q) {
                const int i = q * 256 + tid;
                const int b = i / 320, r2 = i % 320;
                const int te_rel = r2 / 40, fq = r2 % 40;
                st[q] = *reinterpret_cast<const float2*>(
                    x + ((size_t)(bgrp * 16 + b) * TT + te_base + te_rel) * FF + 2 * fq);
            }
        }

        // 2) compute CT timesteps from xa[cur]
        #pragma unroll
        for (int t_off = 0; t_off < CT; ++t_off) {
            short8 A[3];
            #pragma unroll
            for (int kap = 0; kap < 3; ++kap)
                A[kap] = *reinterpret_cast<const short8*>(&xa[cur][t_off][b16][32 * kap + 8 * g]);
            const int t = t0 + ph * CT + t_off;
            #pragma unroll
            for (int tp = 0; tp < 4; ++tp) {
                floatx4 acc = {bias[tp], bias[tp], bias[tp], bias[tp]};
                acc = mfma16(A[0], Bf[tp][0], acc);
                acc = mfma16(A[1], Bf[tp][1], acc);
                acc = mfma16(A[2], Bf[tp][2], acc);
                const int n = 64 * wv + 16 * tp + b16;
                uint2 u2;
                u2.x = packbf2(acc[0], acc[1]);
                u2.y = packbf2(acc[2], acc[3]);
                *reinterpret_cast<uint2*>(
                    reinterpret_cast<__hip_bfloat16*>(pre) +
                    ((size_t)dgrp * TT + t) * 4096 + n * 16 + 4 * g) = u2;
            }
        }

        // 3) write staged data to the other buffer (compiler waits vmcnt here)
        if (have) {
            #pragma unroll
            for (int q = 0; q < 20; ++q) {
                const int i = q * 256 + tid;
                const int b = i / 320, r2 = i % 320;
                const int te_rel = r2 / 40, fq = r2 % 40;
                const int t_off = dir ? (CT - 1 - te_rel) : te_rel;
                *reinterpret_cast<unsigned*>(&xa[cur ^ 1][t_off][b][2 * fq]) = packbf2(st[q].x, st[q].y);
            }
        }
        bar_lgkm();   // LDS only — PRE stores keep flying
    }
}

// ---------------------------------------------------------------------------
// SCAN (MFMA): block = (dir, bgrp) -> 16 batches. Per step:
//   G[16x256] = H[16x64] @ W_hh^T + PRE  via 8 MFMAs/wave; W_hh in registers.
// Wave wv owns tiles {wv, wv+4, wv+8, wv+12} => lane holds i,f,g,o of the same
// (batch,unit) => lane-local c/h update. H round-trips through a 4KB
// double-buffered XOR-swizzled LDS tile; one lgkm-only barrier per step.
// ---------------------------------------------------------------------------
__global__ __launch_bounds__(256, 1)
void lstm_scan_mfma(const __hip_bfloat16* __restrict__ pre,
                    const float* __restrict__ w_hh_f, const float* __restrict__ w_hh_b,
                    float* __restrict__ h_out)   // [2][NB][HH] f32
{
    const int blk  = blockIdx.x;       // 16 = 2 dir x 8 bgrp
    const int dir  = blk >> 3;
    const int bgrp = blk & 7;
    const int dgrp = dir * 8 + bgrp;
    const int tid  = threadIdx.x;
    const int wv   = tid >> 6;         // unit-group (16 units each)
    const int l    = tid & 63;
    const int b16  = l & 15;           // A row (batch) / C col (unit within tile)
    const int g    = l >> 4;           // k-group / C row group

    const float* __restrict__ whh = dir ? w_hh_b : w_hh_f;

    // B-fragments (register-resident for the whole scan):
    // tile tau = wv + 4*gt  -> col n = 16*tau + b16 ; k = 32*kap + 8*g + j
    short8 Bf[4][2];
    #pragma unroll
    for (int gt = 0; gt < 4; ++gt) {
        const int n = 16 * (wv + 4 * gt) + b16;
        #pragma unroll
        for (int kap = 0; kap < 2; ++kap) {
            const float4 v0 = *reinterpret_cast<const float4*>(whh + n * HH + 32 * kap + 8 * g);
            const float4 v1 = *reinterpret_cast<const float4*>(whh + n * HH + 32 * kap + 8 * g + 4);
            short8 s;
            s[0]=f2bf(v0.x); s[1]=f2bf(v0.y); s[2]=f2bf(v0.z); s[3]=f2bf(v0.w);
            s[4]=f2bf(v1.x); s[5]=f2bf(v1.y); s[6]=f2bf(v1.z); s[7]=f2bf(v1.w);
            Bf[gt][kap] = s;
        }
    }

    // H LDS: [buf][16 rows][8 chunks of 16B], XOR-swizzled chunk index.
    __shared__ __align__(16) char Hl[2][2048];
    for (int i = tid; i < 1024; i += 256)
        reinterpret_cast<float*>(&Hl[0][0])[i] = 0.0f;

    // A-read byte offsets (chunk q = (4*kap+g) ^ (b16&7)):
    const int aoff0 = b16 * 128 + (((0 + g) ^ (b16 & 7)) << 4);
    const int aoff1 = b16 * 128 + (((4 + g) ^ (b16 & 7)) << 4);
    // h-write offsets: row b_r = 4*g + r, unit u = 16*wv + b16
    const int u    = 16 * wv + b16;
    int hoff[4];
    #pragma unroll
    for (int r = 0; r < 4; ++r) {
        const int br = 4 * g + r;
        const int q  = (u >> 3) ^ (br & 7);
        hoff[r] = br * 128 + q * 16 + (u & 7) * 2;
    }

    // PRE per-lane base: elem = (dgrp*TT + t)*4096 + n*16 + 4*g, n = 16*(wv+4gt)+b16
    const char* prelane = reinterpret_cast<const char*>(
        pre + (size_t)dgrp * TT * 4096 + (16 * wv + b16) * 16 + 4 * g);
    // per t: +8192 bytes ; per gt: +2048 bytes

    // prime distance-4 PRE prefetch ring
    uint2 pr[4][4];
    #pragma unroll
    for (int d = 0; d < 4; ++d) {
        const char* pb = prelane + (size_t)d * 8192;
        pr[d][0] = *reinterpret_cast<const uint2*>(pb);
        pr[d][1] = *reinterpret_cast<const uint2*>(pb + 2048);
        pr[d][2] = *reinterpret_cast<const uint2*>(pb + 4096);
        pr[d][3] = *reinterpret_cast<const uint2*>(pb + 6144);
    }
    __syncthreads();

    float c4[4] = {0.f, 0.f, 0.f, 0.f};
    float h4[4] = {0.f, 0.f, 0.f, 0.f};

    #pragma unroll 1
    for (int t = 0; t < TT; t += 4) {
        #pragma unroll
        for (int d = 0; d < 4; ++d) {
            const int cur = d & 1;          // (t+d)&1, t % 4 == 0
            const int nxt = cur ^ 1;

            // A fragments from current H buffer
            const short8 a0 = *reinterpret_cast<const short8*>(Hl[cur] + aoff0);
            const short8 a1 = *reinterpret_cast<const short8*>(Hl[cur] + aoff1);

            // accumulators init = PRE (i, f, g, o tiles)
            floatx4 ai, af, ag, ao;
            { const uint2 p = pr[d][0]; ai = (floatx4){bflo(p.x), bfhi(p.x), bflo(p.y), bfhi(p.y)}; }
            { const uint2 p = pr[d][1]; af = (floatx4){bflo(p.x), bfhi(p.x), bflo(p.y), bfhi(p.y)}; }
            { const uint2 p = pr[d][2]; ag = (floatx4){bflo(p.x), bfhi(p.x), bflo(p.y), bfhi(p.y)}; }
            { const uint2 p = pr[d][3]; ao = (floatx4){bflo(p.x), bfhi(p.x), bflo(p.y), bfhi(p.y)}; }

            // issue prefetch for t+d+4 (clamped; last group's loads unused)
            {
                int tp = t + d + 4; if (tp >= TT) tp = 0;
                const char* pb = prelane + (size_t)tp * 8192;
                pr[d][0] = *reinterpret_cast<const uint2*>(pb);
                pr[d][1] = *reinterpret_cast<const uint2*>(pb + 2048);
                pr[d][2] = *reinterpret_cast<const uint2*>(pb + 4096);
                pr[d][3] = *reinterpret_cast<const uint2*>(pb + 6144);
            }

            // G = H @ W_hh^T + PRE
            ai = mfma16(a1, Bf[0][1], mfma16(a0, Bf[0][0], ai));
            af = mfma16(a1, Bf[1][1], mfma16(a0, Bf[1][0], af));
            ag = mfma16(a1, Bf[2][1], mfma16(a0, Bf[2][0], ag));
            ao = mfma16(a1, Bf[3][1], mfma16(a0, Bf[3][0], ao));

            // lane-local LSTM cell update (4 batches per lane)
            #pragma unroll
            for (int r = 0; r < 4; ++r) {
                c4[r] = sigm(af[r]) * c4[r] + sigm(ai[r]) * tanh_f(ag[r]);
                h4[r] = sigm(ao[r]) * tanh_f(c4[r]);
                *reinterpret_cast<short*>(Hl[nxt] + hoff[r]) = f2bf(h4[r]);
            }
            bar_lgkm();   // LDS visibility only; PRE prefetch stays in flight
        }
    }

    #pragma unroll
    for (int r = 0; r < 4; ++r)
        h_out[(size_t)(dir * NB + bgrp * 16 + 4 * g + r) * HH + u] = h4[r];
}

// ---------------------------------------------------------------------------
// Fallback: fully fused scan (round-1 kernel) if ws is too small for PRE.
// ---------------------------------------------------------------------------
__global__ __launch_bounds__(256, 1)
void lstm_scan_fused_kernel(const float* __restrict__ x,
                            const float* __restrict__ w_ih_f, const float* __restrict__ w_hh_f,
                            const float* __restrict__ b_ih_f, const float* __restrict__ b_hh_f,
                            const float* __restrict__ w_ih_b, const float* __restrict__ w_hh_b,
                            const float* __restrict__ b_ih_b, const float* __restrict__ b_hh_b,
                            float* __restrict__ h_out)
{
    const int blk = blockIdx.x;
    const int dir = blk >> 7;
    const int bat = blk & 127;
    const int tid = threadIdx.x;
    const int wv  = tid >> 6;
    const int ln  = tid & 63;

    const float* __restrict__ w_ih = dir ? w_ih_b : w_ih_f;
    const float* __restrict__ w_hh = dir ? w_hh_b : w_hh_f;
    const float* __restrict__ b_ih = dir ? b_ih_b : b_ih_f;
    const float* __restrict__ b_hh = dir ? b_hh_b : b_hh_f;

    float wi[FF], wh[HH];
    #pragma unroll
    for (int f = 0; f < FF; ++f) wi[f] = w_ih[tid * FF + f];
    #pragma unroll
    for (int j = 0; j < HH; ++j) wh[j] = w_hh[tid * HH + j];
    const float bias = b_ih[tid] + b_hh[tid];

    __shared__ float xs[2][FF];
    __shared__ float hbuf[4][HH];
    __shared__ float gbuf[2][256];

    const float* __restrict__ xrow = x + (size_t)bat * (TT * FF);
    float c = 0.0f, hreg = 0.0f;
    hbuf[wv][ln] = 0.0f;

    float xA = 0.0f;
    if (tid < FF) {
        xs[0][tid] = xrow[(size_t)(dir ? (TT - 1) : 0) * FF + tid];
        xA         = xrow[(size_t)(dir ? (TT - 2) : 1) * FF + tid];
    }
    __syncthreads();

    #pragma unroll 1
    for (int t = 0; t < TT; ++t) {
        const int cur = t & 1, nxt = cur ^ 1;
        float a0 = 0.f, a1 = 0.f, a2 = 0.f, a3 = 0.f;
        const float4* xs4 = reinterpret_cast<const float4*>(xs[cur]);
        #pragma unroll
        for (int f = 0; f < FF / 4; ++f) {
            float4 v = xs4[f];
            a0 = fmaf(wi[4*f+0], v.x, a0);
            a1 = fmaf(wi[4*f+1], v.y, a1);
            a2 = fmaf(wi[4*f+2], v.z, a2);
            a3 = fmaf(wi[4*f+3], v.w, a3);
        }
        const float4* hb4 = reinterpret_cast<const float4*>(hbuf[wv]);
        #pragma unroll
        for (int j = 0; j < HH / 4; ++j) {
            float4 v = hb4[j];
            a0 = fmaf(wh[4*j+0], v.x, a0);
            a1 = fmaf(wh[4*j+1], v.y, a1);
            a2 = fmaf(wh[4*j+2], v.z, a2);
            a3 = fmaf(wh[4*j+3], v.w, a3);
        }
        gbuf[cur][tid] = ((a0 + a1) + (a2 + a3)) + bias;

        if (tid < FF) {
            if (t + 1 < TT) xs[nxt][tid] = xA;
            if (t + 2 < TT) xA = xrow[(size_t)(dir ? (TT - 3 - t) : (t + 2)) * FF + tid];
        }
        __syncthreads();

        const float gi = gbuf[cur][ln];
        const float gf = gbuf[cur][64 + ln];
        const float gg = gbuf[cur][128 + ln];
        const float go = gbuf[cur][192 + ln];
        c    = sigm(gf) * c + sigm(gi) * tanh_f(gg);
        hreg = sigm(go) * tanh_f(c);
        hbuf[wv][ln] = hreg;
    }

    if (tid < HH) h_out[(size_t)(dir * 128 + bat) * HH + tid] = hreg;
}

__global__ __launch_bounds__(64, 1)
void fc_kernel(const float* __restrict__ h_out,   // [2][NB][HH]
               const float* __restrict__ w_fc,    // [8][128]
               const float* __restrict__ b_fc,    // [8]
               float* __restrict__ out)           // [NB][8]
{
    const int b = blockIdx.x;
    const int o = threadIdx.x;
    if (o < 8) {
        float acc = b_fc[o];
        #pragma unroll 4
        for (int j = 0; j < HH; ++j)
            acc = fmaf(h_out[(size_t)b * HH + j], w_fc[o * 128 + j], acc);
        #pragma unroll 4
        for (int j = 0; j < HH; ++j)
            acc = fmaf(h_out[(size_t)(NB + b) * HH + j], w_fc[o * 128 + 64 + j], acc);
        out[b * 8 + o] = acc;
    }
}

extern "C" void kernel_launch(void* const* d_in, const int* in_sizes, int n_in,
                              void* d_out, int out_size, void* d_ws, size_t ws_size,
                              hipStream_t stream) {
    const float* x      = (const float*)d_in[0];
    const float* w_ih_f = (const float*)d_in[2];
    const float* w_hh_f = (const float*)d_in[3];
    const float* b_ih_f = (const float*)d_in[4];
    const float* b_hh_f = (const float*)d_in[5];
    const float* w_ih_b = (const float*)d_in[6];
    const float* w_hh_b = (const float*)d_in[7];
    const float* b_ih_b = (const float*)d_in[8];
    const float* b_hh_b = (const float*)d_in[9];
    const float* w_fc   = (const float*)d_in[10];
    const float* b_fc   = (const float*)d_in[11];
    float* out = (float*)d_out;

    const size_t pre_bytes = (size_t)2 * NB * TT * 256 * sizeof(__hip_bfloat16); // 512 MiB
    const size_t need      = pre_bytes + 64 * 1024;

    if (ws_size >= need) {
        __hip_bfloat16* pre = (__hip_bfloat16*)d_ws;
        float* h_out = (float*)((char*)d_ws + pre_bytes);
        lstm_proj_mfma<<<dim3(256), dim3(256), 0, stream>>>(
            x, w_ih_f, b_ih_f, b_hh_f, w_ih_b, b_ih_b, b_hh_b, pre);
        lstm_scan_mfma<<<dim3(16), dim3(256), 0, stream>>>(
            pre, w_hh_f, w_hh_b, h_out);
        fc_kernel<<<dim3(128), dim3(64), 0, stream>>>(h_out, w_fc, b_fc, out);
    } else {
        float* h_out = (float*)d_ws;   // 64 KiB
        lstm_scan_fused_kernel<<<dim3(256), dim3(256), 0, stream>>>(
            x, w_ih_f, w_hh_f, b_ih_f, b_hh_f,
            w_ih_b, w_hh_b, b_ih_b, b_hh_b, h_out);
        fc_kernel<<<dim3(128), dim3(64), 0, stream>>>(h_out, w_fc, b_fc, out);
    }
}

// Round 5
// 2094.526 us; speedup vs baseline: 3.3382x; 1.2969x over previous
//
#include <hip/hip_runtime.h>
#include <hip/hip_bf16.h>

#define TT 4096
#define FF 80
#define HH 64
#define NB 128
#define TB 256    // proj: timesteps per block
#define CT 8      // proj: timesteps per staging phase
#define XPAD 104  // proj LDS row stride in bf16 elems

using short8  = __attribute__((ext_vector_type(8))) short;   // 8 bf16 = 4 VGPR
using floatx4 = __attribute__((ext_vector_type(4))) float;

__device__ __forceinline__ float sigm(float x)  { return __builtin_amdgcn_rcpf(1.0f + __expf(-x)); }
__device__ __forceinline__ float tanh_f(float x){ return 1.0f - 2.0f * __builtin_amdgcn_rcpf(1.0f + __expf(2.0f * x)); }

__device__ __forceinline__ unsigned short f2bf(float f) {    // RNE f32->bf16
    unsigned u = __builtin_bit_cast(unsigned, f);
    u += 0x7fffu + ((u >> 16) & 1u);
    return (unsigned short)(u >> 16);
}
__device__ __forceinline__ float bf2f(unsigned short u) {
    return __builtin_bit_cast(float, (unsigned)u << 16);
}
__device__ __forceinline__ unsigned packbf2(float a, float b) {
    return (unsigned)f2bf(a) | ((unsigned)f2bf(b) << 16);
}

// LDS-visibility-only barrier: global loads stay in flight across it.
__device__ __forceinline__ void bar_lgkm() {
    asm volatile("s_waitcnt lgkmcnt(0)" ::: "memory");
    __builtin_amdgcn_s_barrier();
}

__device__ __forceinline__ floatx4 mfma16(short8 a, short8 b, floatx4 c) {
    return __builtin_amdgcn_mfma_f32_16x16x32_bf16(a, b, c, 0, 0, 0);
}

// ---------------------------------------------------------------------------
// PROJ (MFMA): PRE[chain = dir*128+b][t][gate k 0..255] (bf16) =
//   b_ih[k]+b_hh[k] + sum_f w_ih[k][f]*x[b][te][f],  te = t (fwd) / TT-1-t (bwd)
// Block = (dgrp = dir*8+bgrp, ttile). A = x rows (16 batches), B = w_ih^T,
// K = 80 zero-padded to 96. B-frags register-resident. Double-buffered LDS
// staging with issue-early/write-late (T14 style).
// ---------------------------------------------------------------------------
__global__ __launch_bounds__(256, 1)
void lstm_proj_mfma(const float* __restrict__ x,
                    const float* __restrict__ w_ih_f, const float* __restrict__ b_ih_f,
                    const float* __restrict__ b_hh_f,
                    const float* __restrict__ w_ih_b, const float* __restrict__ b_ih_b,
                    const float* __restrict__ b_hh_b,
                    unsigned short* __restrict__ pre)
{
    const int blk   = blockIdx.x;        // 256 = 16 dgrp x 16 ttile
    const int ttile = blk & 15;
    const int dgrp  = blk >> 4;
    const int dir   = dgrp >> 3;
    const int bgrp  = dgrp & 7;
    const int tid   = threadIdx.x;
    const int wv    = tid >> 6;
    const int l     = tid & 63;
    const int b16   = l & 15;            // A row (batch) / C col (n within tile)
    const int g     = l >> 4;            // k-group / C row group
    const int t0    = ttile * TB;

    const float* __restrict__ wih = dir ? w_ih_b : w_ih_f;
    const float* __restrict__ bi  = dir ? b_ih_b : b_ih_f;
    const float* __restrict__ bh  = dir ? b_hh_b : b_hh_f;

    // B-fragments: wave wv owns tiles tau = 4*wv + tp. col n = 16*tau + b16,
    // k = 32*kap + 8*g + j (zero for k >= 80).
    short8 Bf[4][3];
    float  bias[4];
    #pragma unroll
    for (int tp = 0; tp < 4; ++tp) {
        const int n = 64 * wv + 16 * tp + b16;
        bias[tp] = bi[n] + bh[n];
        #pragma unroll
        for (int kap = 0; kap < 3; ++kap) {
            const int f0 = 32 * kap + 8 * g;
            float f[8];
            if (f0 < FF) {
                const float4 v0 = *reinterpret_cast<const float4*>(wih + n * FF + f0);
                const float4 v1 = *reinterpret_cast<const float4*>(wih + n * FF + f0 + 4);
                f[0]=v0.x; f[1]=v0.y; f[2]=v0.z; f[3]=v0.w;
                f[4]=v1.x; f[5]=v1.y; f[6]=v1.z; f[7]=v1.w;
            } else {
                #pragma unroll
                for (int j = 0; j < 8; ++j) f[j] = 0.0f;
            }
            short8 s;
            #pragma unroll
            for (int j = 0; j < 8; ++j) s[j] = (short)f2bf(f[j]);
            Bf[tp][kap] = s;
        }
    }

    // x staging LDS: [buf][CT t][16 b][XPAD] bf16; cols 80..103 stay zero.
    __shared__ __align__(16) unsigned short xa[2][CT][16][XPAD];
    for (int i = tid; i < 2 * CT * 16 * XPAD / 2; i += 256)
        reinterpret_cast<unsigned*>(&xa[0][0][0][0])[i] = 0u;
    __syncthreads();

    const int nph = TB / CT;   // 32

    {   // prologue: stage phase 0 into xa[0]
        const int t0p = t0;
        const int te_base = dir ? (TT - CT - t0p) : t0p;
        float2 st[20];
        #pragma unroll
        for (int q = 0; q < 20; ++q) {
            const int i = q * 256 + tid;
            const int b = i / 320, r2 = i % 320;
            const int te_rel = r2 / 40, fq = r2 % 40;
            st[q] = *reinterpret_cast<const float2*>(
                x + ((size_t)(bgrp * 16 + b) * TT + te_base + te_rel) * FF + 2 * fq);
        }
        #pragma unroll
        for (int q = 0; q < 20; ++q) {
            const int i = q * 256 + tid;
            const int b = i / 320, r2 = i % 320;
            const int te_rel = r2 / 40, fq = r2 % 40;
            const int t_off = dir ? (CT - 1 - te_rel) : te_rel;
            *reinterpret_cast<unsigned*>(&xa[0][t_off][b][2 * fq]) = packbf2(st[q].x, st[q].y);
        }
    }
    __syncthreads();

    #pragma unroll 1
    for (int ph = 0; ph < nph; ++ph) {
        const int cur = ph & 1;
        const bool have = (ph + 1) < nph;

        // 1) issue next-phase global loads early (hide under MFMA phase)
        float2 st[20];
        if (have) {
            const int t0p = t0 + (ph + 1) * CT;
            const int te_base = dir ? (TT - CT - t0p) : t0p;
            #pragma unroll
            for (int q = 0; q < 20; ++q) {
                const int i = q * 256 + tid;
                const int b = i / 320, r2 = i % 320;
                const int te_rel = r2 / 40, fq = r2 % 40;
                st[q] = *reinterpret_cast<const float2*>(
                    x + ((size_t)(bgrp * 16 + b) * TT + te_base + te_rel) * FF + 2 * fq);
            }
        }

        // 2) compute CT timesteps from xa[cur]
        #pragma unroll
        for (int t_off = 0; t_off < CT; ++t_off) {
            short8 A[3];
            #pragma unroll
            for (int kap = 0; kap < 3; ++kap)
                A[kap] = *reinterpret_cast<const short8*>(&xa[cur][t_off][b16][32 * kap + 8 * g]);
            const int t = t0 + ph * CT + t_off;
            #pragma unroll
            for (int tp = 0; tp < 4; ++tp) {
                floatx4 acc = {bias[tp], bias[tp], bias[tp], bias[tp]};
                acc = mfma16(A[0], Bf[tp][0], acc);
                acc = mfma16(A[1], Bf[tp][1], acc);
                acc = mfma16(A[2], Bf[tp][2], acc);
                const int n = 64 * wv + 16 * tp + b16;
                // C row = batch 4g+r, col = n. Store PRE[chain][t][n].
                #pragma unroll
                for (int r = 0; r < 4; ++r) {
                    const int bb = dir * NB + bgrp * 16 + 4 * g + r;
                    pre[((size_t)bb * TT + t) * 256 + n] = f2bf(acc[r]);
                }
            }
        }

        // 3) write staged data to the other buffer
        if (have) {
            #pragma unroll
            for (int q = 0; q < 20; ++q) {
                const int i = q * 256 + tid;
                const int b = i / 320, r2 = i % 320;
                const int te_rel = r2 / 40, fq = r2 % 40;
                const int t_off = dir ? (CT - 1 - te_rel) : te_rel;
                *reinterpret_cast<unsigned*>(&xa[cur ^ 1][t_off][b][2 * fq]) = packbf2(st[q].x, st[q].y);
            }
        }
        bar_lgkm();   // LDS only — PRE stores keep flying
    }
}

// ---------------------------------------------------------------------------
// SCAN (VALU, 256 blocks = 1 chain/CU): thread k = gate k, its 64 W_hh weights
// in 16 explicit float4 REGISTERS (scalar locals, not arrays -> no sinking).
// Per step: 64 FMA vs per-wave hbuf broadcast; transposed gbufT gives the
// activation phase one ds_read_b128; one lgkm-only barrier per step; PRE
// prefetched distance-4 (stays in flight across the barrier). Transcendentals
// now spread over 256 CUs instead of 16.
// ---------------------------------------------------------------------------
#define MAC(W,H) a0 = fmaf((W).x,(H).x,a0); a1 = fmaf((W).y,(H).y,a1); \
                 a2 = fmaf((W).z,(H).z,a2); a3 = fmaf((W).w,(H).w,a3);

__global__ __launch_bounds__(256, 1)
void lstm_scan_valu(const unsigned short* __restrict__ pre,  // [256][TT][256]
                    const float* __restrict__ w_hh_f, const float* __restrict__ w_hh_b,
                    float* __restrict__ h_out)               // [256][64]
{
    const int chain = blockIdx.x;       // dir*128 + bat
    const int dir   = chain >> 7;
    const int tid   = threadIdx.x;      // gate index k (wv = gate type)
    const int wv    = tid >> 6;
    const int ln    = tid & 63;

    const float4* wr = reinterpret_cast<const float4*>(
        (dir ? w_hh_b : w_hh_f) + tid * HH);
    // 16 scalar float4 locals: SSA values -> guaranteed register-resident.
    const float4 w0 = wr[0],  w1 = wr[1],  w2 = wr[2],  w3 = wr[3];
    const float4 w4 = wr[4],  w5 = wr[5],  w6 = wr[6],  w7 = wr[7];
    const float4 w8 = wr[8],  w9 = wr[9],  wA = wr[10], wB = wr[11];
    const float4 wC = wr[12], wD = wr[13], wE = wr[14], wF = wr[15];

    __shared__ float hbuf[4][HH];        // per-wave private h copy (f32)
    __shared__ float gbufT[2][HH][4];    // [parity][unit][gate], b128-readable

    hbuf[wv][ln] = 0.0f;

    const unsigned short* __restrict__ prow =
        pre + (size_t)chain * TT * 256 + tid;
    unsigned short pr[4];                // distance-4 prefetch ring
    #pragma unroll
    for (int d = 0; d < 4; ++d) pr[d] = prow[d * 256];

    float c = 0.0f, h = 0.0f;
    __syncthreads();

    #pragma unroll 1
    for (int t = 0; t < TT; t += 4) {
        #pragma unroll
        for (int d = 0; d < 4; ++d) {
            const int cur = d & 1;

            const float4* hb = reinterpret_cast<const float4*>(hbuf[wv]);
            float a0 = 0.f, a1 = 0.f, a2 = 0.f, a3 = 0.f;
            MAC(w0, hb[0]);  MAC(w1, hb[1]);  MAC(w2, hb[2]);  MAC(w3, hb[3]);
            MAC(w4, hb[4]);  MAC(w5, hb[5]);  MAC(w6, hb[6]);  MAC(w7, hb[7]);
            MAC(w8, hb[8]);  MAC(w9, hb[9]);  MAC(wA, hb[10]); MAC(wB, hb[11]);
            MAC(wC, hb[12]); MAC(wD, hb[13]); MAC(wE, hb[14]); MAC(wF, hb[15]);

            const float gate = ((a0 + a1) + (a2 + a3)) + bf2f(pr[d]);
            gbufT[cur][ln][wv] = gate;

            // reload ring slot for t+d+4 (wraps harmlessly near the end);
            // issued before the barrier, stays in flight across it.
            pr[d] = prow[(size_t)((t + d + 4) & (TT - 1)) * 256];

            bar_lgkm();                  // LDS visibility only

            const float4 g4 = *reinterpret_cast<const float4*>(gbufT[cur][ln]);
            const float si = sigm(g4.x), sf = sigm(g4.y);
            const float tg = tanh_f(g4.z), so = sigm(g4.w);
            c = fmaf(sf, c, si * tg);
            h = so * tanh_f(c);
            hbuf[wv][ln] = h;            // own-wave buffer: no 2nd barrier
        }
    }

    if (tid < HH) h_out[(size_t)chain * HH + tid] = h;
}

// ---------------------------------------------------------------------------
// Fallback: fully fused scan (round-1 kernel) if ws is too small for PRE.
// ---------------------------------------------------------------------------
__global__ __launch_bounds__(256, 1)
void lstm_scan_fused_kernel(const float* __restrict__ x,
                            const float* __restrict__ w_ih_f, const float* __restrict__ w_hh_f,
                            const float* __restrict__ b_ih_f, const float* __restrict__ b_hh_f,
                            const float* __restrict__ w_ih_b, const float* __restrict__ w_hh_b,
                            const float* __restrict__ b_ih_b, const float* __restrict__ b_hh_b,
                            float* __restrict__ h_out)
{
    const int blk = blockIdx.x;
    const int dir = blk >> 7;
    const int bat = blk & 127;
    const int tid = threadIdx.x;
    const int wv  = tid >> 6;
    const int ln  = tid & 63;

    const float* __restrict__ w_ih = dir ? w_ih_b : w_ih_f;
    const float* __restrict__ w_hh = dir ? w_hh_b : w_hh_f;
    const float* __restrict__ b_ih = dir ? b_ih_b : b_ih_f;
    const float* __restrict__ b_hh = dir ? b_hh_b : b_hh_f;

    float wi[FF], wh[HH];
    #pragma unroll
    for (int f = 0; f < FF; ++f) wi[f] = w_ih[tid * FF + f];
    #pragma unroll
    for (int j = 0; j < HH; ++j) wh[j] = w_hh[tid * HH + j];
    const float bias = b_ih[tid] + b_hh[tid];

    __shared__ float xs[2][FF];
    __shared__ float hbuf[4][HH];
    __shared__ float gbuf[2][256];

    const float* __restrict__ xrow = x + (size_t)bat * (TT * FF);
    float c = 0.0f, hreg = 0.0f;
    hbuf[wv][ln] = 0.0f;

    float xA = 0.0f;
    if (tid < FF) {
        xs[0][tid] = xrow[(size_t)(dir ? (TT - 1) : 0) * FF + tid];
        xA         = xrow[(size_t)(dir ? (TT - 2) : 1) * FF + tid];
    }
    __syncthreads();

    #pragma unroll 1
    for (int t = 0; t < TT; ++t) {
        const int cur = t & 1, nxt = cur ^ 1;
        float a0 = 0.f, a1 = 0.f, a2 = 0.f, a3 = 0.f;
        const float4* xs4 = reinterpret_cast<const float4*>(xs[cur]);
        #pragma unroll
        for (int f = 0; f < FF / 4; ++f) {
            float4 v = xs4[f];
            a0 = fmaf(wi[4*f+0], v.x, a0);
            a1 = fmaf(wi[4*f+1], v.y, a1);
            a2 = fmaf(wi[4*f+2], v.z, a2);
            a3 = fmaf(wi[4*f+3], v.w, a3);
        }
        const float4* hb4 = reinterpret_cast<const float4*>(hbuf[wv]);
        #pragma unroll
        for (int j = 0; j < HH / 4; ++j) {
            float4 v = hb4[j];
            a0 = fmaf(wh[4*j+0], v.x, a0);
            a1 = fmaf(wh[4*j+1], v.y, a1);
            a2 = fmaf(wh[4*j+2], v.z, a2);
            a3 = fmaf(wh[4*j+3], v.w, a3);
        }
        gbuf[cur][tid] = ((a0 + a1) + (a2 + a3)) + bias;

        if (tid < FF) {
            if (t + 1 < TT) xs[nxt][tid] = xA;
            if (t + 2 < TT) xA = xrow[(size_t)(dir ? (TT - 3 - t) : (t + 2)) * FF + tid];
        }
        __syncthreads();

        const float gi = gbuf[cur][ln];
        const float gf = gbuf[cur][64 + ln];
        const float gg = gbuf[cur][128 + ln];
        const float go = gbuf[cur][192 + ln];
        c    = sigm(gf) * c + sigm(gi) * tanh_f(gg);
        hreg = sigm(go) * tanh_f(c);
        hbuf[wv][ln] = hreg;
    }

    if (tid < HH) h_out[(size_t)(dir * 128 + bat) * HH + tid] = hreg;
}

__global__ __launch_bounds__(64, 1)
void fc_kernel(const float* __restrict__ h_out,   // [2][NB][HH]
               const float* __restrict__ w_fc,    // [8][128]
               const float* __restrict__ b_fc,    // [8]
               float* __restrict__ out)           // [NB][8]
{
    const int b = blockIdx.x;
    const int o = threadIdx.x;
    if (o < 8) {
        float acc = b_fc[o];
        #pragma unroll 4
        for (int j = 0; j < HH; ++j)
            acc = fmaf(h_out[(size_t)b * HH + j], w_fc[o * 128 + j], acc);
        #pragma unroll 4
        for (int j = 0; j < HH; ++j)
            acc = fmaf(h_out[(size_t)(NB + b) * HH + j], w_fc[o * 128 + 64 + j], acc);
        out[b * 8 + o] = acc;
    }
}

extern "C" void kernel_launch(void* const* d_in, const int* in_sizes, int n_in,
                              void* d_out, int out_size, void* d_ws, size_t ws_size,
                              hipStream_t stream) {
    const float* x      = (const float*)d_in[0];
    const float* w_ih_f = (const float*)d_in[2];
    const float* w_hh_f = (const float*)d_in[3];
    const float* b_ih_f = (const float*)d_in[4];
    const float* b_hh_f = (const float*)d_in[5];
    const float* w_ih_b = (const float*)d_in[6];
    const float* w_hh_b = (const float*)d_in[7];
    const float* b_ih_b = (const float*)d_in[8];
    const float* b_hh_b = (const float*)d_in[9];
    const float* w_fc   = (const float*)d_in[10];
    const float* b_fc   = (const float*)d_in[11];
    float* out = (float*)d_out;

    const size_t pre_bytes = (size_t)2 * NB * TT * 256 * 2;   // 512 MiB bf16
    const size_t need      = pre_bytes + 64 * 1024;

    if (ws_size >= need) {
        unsigned short* pre = (unsigned short*)d_ws;
        float* h_out = (float*)((char*)d_ws + pre_bytes);
        lstm_proj_mfma<<<dim3(256), dim3(256), 0, stream>>>(
            x, w_ih_f, b_ih_f, b_hh_f, w_ih_b, b_ih_b, b_hh_b, pre);
        lstm_scan_valu<<<dim3(256), dim3(256), 0, stream>>>(
            pre, w_hh_f, w_hh_b, h_out);
        fc_kernel<<<dim3(128), dim3(64), 0, stream>>>(h_out, w_fc, b_fc, out);
    } else {
        float* h_out = (float*)d_ws;   // 64 KiB
        lstm_scan_fused_kernel<<<dim3(256), dim3(256), 0, stream>>>(
            x, w_ih_f, w_hh_f, b_ih_f, b_hh_f,
            w_ih_b, w_hh_b, b_ih_b, b_hh_b, h_out);
        fc_kernel<<<dim3(128), dim3(64), 0, stream>>>(h_out, w_fc, b_fc, out);
    }
}